// Round 1
// 282.286 us; speedup vs baseline: 1.1375x; 1.1375x over previous
//
#include <hip/hip_runtime.h>
#include <hip/hip_bf16.h>
#include <math.h>

#define HC 64
#define DD 128
#define NPB 32      // nodes per block in node_transform (4 waves x 8 nodes)
#define BSH 7       // bucket = 128 consecutive ids
#define BW  128
#define KMAX 512    // max buckets; ids must fit 16 bits (N <= 65536)
#define CHUNK 4096  // edges per partition/hist workgroup
#define CAP 8192    // LDS sort capacity in bucket_csr (entries)

// ---------------- node transform (both graphs in one grid) ----------------
// xs = elu(x)@Wsrc (bf16); logits PRESCALED by log2(e) for hw exp2
// (leaky_relu is positively homogeneous: leaky(c*a)=c*leaky(a), c>0).
__global__ __launch_bounds__(256) void node_transform2(
    const float* __restrict__ xH, const float* __restrict__ xT,
    const float* __restrict__ Wsrc, const float* __restrict__ Wdst,
    const float* __restrict__ att_src, const float* __restrict__ att_dst,
    __hip_bfloat16* __restrict__ xsH, __hip_bfloat16* __restrict__ xsT,
    float* __restrict__ lsH, float* __restrict__ ldH,
    float* __restrict__ lsT, float* __restrict__ ldT,
    int NH, int NT, int blocksH)
{
  const float* x; __hip_bfloat16* xs_out; float* logit_s; float* logit_d;
  int N, blk;
  if ((int)blockIdx.x < blocksH) { x = xH; xs_out = xsH; logit_s = lsH; logit_d = ldH; N = NH; blk = blockIdx.x; }
  else { x = xT; xs_out = xsT; logit_s = lsT; logit_d = ldT; N = NT; blk = blockIdx.x - blocksH; }

  __shared__ float sx[NPB * DD];       // 16 KB
  int tid = threadIdx.x;
  int nbase = blk * NPB;
  for (int i = tid; i < NPB * DD; i += 256) {
    int n = nbase + (i >> 7);
    float v = 0.f;
    if (n < N) {
      v = x[(size_t)n * DD + (i & 127)];
      v = (v > 0.f) ? v : (exp2f(v * 1.44269504f) - 1.f);   // elu
    }
    sx[i] = v;
  }
  __syncthreads();

  const float LOG2E = 1.44269504f;
  int j = tid & 63;
  int wid = tid >> 6;
  float as = att_src[j] * LOG2E;
  float ad = att_dst[j] * LOG2E;

  float accs[8], accd[8];
  #pragma unroll
  for (int m = 0; m < 8; ++m) { accs[m] = 0.f; accd[m] = 0.f; }

  const float* xbase = &sx[wid * 8 * DD];
  for (int k = 0; k < DD; k += 4) {
    float ws[4], wd[4];
    #pragma unroll
    for (int kk = 0; kk < 4; ++kk) {
      ws[kk] = Wsrc[(k + kk) * HC + j];
      wd[kk] = Wdst[(k + kk) * HC + j];
    }
    #pragma unroll
    for (int m = 0; m < 8; ++m) {
      const float4 xv = *(const float4*)&xbase[m * DD + k];
      accs[m] = fmaf(xv.x, ws[0], accs[m]);
      accd[m] = fmaf(xv.x, wd[0], accd[m]);
      accs[m] = fmaf(xv.y, ws[1], accs[m]);
      accd[m] = fmaf(xv.y, wd[1], accd[m]);
      accs[m] = fmaf(xv.z, ws[2], accs[m]);
      accd[m] = fmaf(xv.z, wd[2], accd[m]);
      accs[m] = fmaf(xv.w, ws[3], accs[m]);
      accd[m] = fmaf(xv.w, wd[3], accd[m]);
    }
  }

  #pragma unroll
  for (int m = 0; m < 8; ++m) {
    int n = nbase + wid * 8 + m;
    if (n >= N) break;
    xs_out[(size_t)n * HC + j] = __float2bfloat16(accs[m]);
    float ps = accs[m] * as;
    float pd = accd[m] * ad;
    #pragma unroll
    for (int off = 16; off > 0; off >>= 1) {
      ps += __shfl_xor(ps, off, 64);
      pd += __shfl_xor(pd, off, 64);
    }
    if ((j & 31) == 0) {
      int h = j >> 5;
      logit_s[n * 2 + h] = ps;
      logit_d[n * 2 + h] = pd;
    }
  }
}

// ---------------- counting sort ----------------
__global__ __launch_bounds__(256) void hist_both(
    const int* __restrict__ src, const int* __restrict__ dst, int E, int NL,
    int* __restrict__ histA, int* __restrict__ histB, int KA, int KB, int B)
{
  __shared__ int hA[KMAX];
  __shared__ int hB[KMAX];
  int tid = threadIdx.x, bid = blockIdx.x;
  for (int i = tid; i < KA; i += 256) hA[i] = 0;
  for (int i = tid; i < KB; i += 256) hB[i] = 0;
  __syncthreads();
  int base = bid * CHUNK;
  int E2 = E + NL;
  int lim = base + CHUNK < E2 ? base + CHUNK : E2;
  for (int i = base + tid; i < lim; i += 256) {
    int s, d;
    if (i < E) { s = src[i]; d = dst[i]; } else { s = d = i - E; }
    atomicAdd(&hA[d >> BSH], 1);
    atomicAdd(&hB[s >> BSH], 1);
  }
  __syncthreads();
  for (int k = tid; k < KA; k += 256) histA[(size_t)k * B + bid] = hA[k];
  for (int k = tid; k < KB; k += 256) histB[(size_t)k * B + bid] = hB[k];
}

// one WAVE per bucket: exclusive scan of its B chunk counts; emit totals
__global__ __launch_bounds__(256) void scan_hist(
    int* __restrict__ histA, int KA, int* __restrict__ histB, int KB, int B,
    int* __restrict__ totals)
{
  int j = blockIdx.x * 4 + (threadIdx.x >> 6);
  if (j >= KA + KB) return;
  int lane = threadIdx.x & 63;
  int* rowp = (j < KA) ? &histA[(size_t)j * B] : &histB[(size_t)(j - KA) * B];
  int carry = 0;
  for (int c0 = 0; c0 < B; c0 += 64) {
    int c = c0 + lane;
    int v = (c < B) ? rowp[c] : 0;
    int inc = v;
    #pragma unroll
    for (int off = 1; off < 64; off <<= 1) {
      int u = __shfl_up(inc, off, 64);
      if (lane >= off) inc += u;
    }
    if (c < B) rowp[c] = inc - v + carry;
    carry += __shfl(inc, 63, 64);
  }
  if (lane == 0) totals[j] = carry;
}

__global__ __launch_bounds__(1024) void scan_totals(
    const int* __restrict__ totals, int KA, int KB, int E2,
    int* __restrict__ offA, int* __restrict__ offB)
{
  __shared__ int buf[1024];
  int t = threadIdx.x;
  int v = (t < KA) ? totals[t] : 0;
  buf[t] = v; __syncthreads();
  #pragma unroll
  for (int off = 1; off < 1024; off <<= 1) {
    int u = (t >= off) ? buf[t - off] : 0;
    __syncthreads(); buf[t] += u; __syncthreads();
  }
  if (t < KA) offA[t] = buf[t] - v;
  if (t == 0) offA[KA] = E2;
  __syncthreads();
  int v2 = (t < KB) ? totals[KA + t] : 0;
  buf[t] = v2; __syncthreads();
  #pragma unroll
  for (int off = 1; off < 1024; off <<= 1) {
    int u = (t >= off) ? buf[t - off] : 0;
    __syncthreads(); buf[t] += u; __syncthreads();
  }
  if (t < KB) offB[t] = buf[t] - v2;
  if (t == 0) offB[KB] = E2;
}

// partition into bucket-contiguous segments. word = other | (key << 16);
// bucket recovered as w >> (16+BSH) (no search). blockIdx.y selects pass.
__global__ __launch_bounds__(256) void partition_edges(
    const int* __restrict__ src, const int* __restrict__ dst, int E, int NL,
    const int* __restrict__ histA, const int* __restrict__ offA,
    const int* __restrict__ histB, const int* __restrict__ offB,
    unsigned int* __restrict__ partA, unsigned int* __restrict__ partB,
    int KA, int KB, int B)
{
  __shared__ unsigned int stage[CHUNK];  // 16 KB
  __shared__ int lbase[KMAX];
  __shared__ int lcur[KMAX];
  __shared__ int gbase[KMAX];
  int tid = threadIdx.x, bid = blockIdx.x;
  int pass = blockIdx.y;
  const int K = pass ? KB : KA;
  const int* hist = pass ? histB : histA;
  const int* off  = pass ? offB : offA;
  unsigned int* out = pass ? partB : partA;

  int base = bid * CHUNK;
  int E2 = E + NL;
  int lim = base + CHUNK < E2 ? base + CHUNK : E2;
  int cnt = lim - base;

  for (int i = tid; i < K; i += 256) lbase[i] = 0;
  __syncthreads();
  for (int i = base + tid; i < lim; i += 256) {
    int s, d;
    if (i < E) { s = src[i]; d = dst[i]; } else { s = d = i - E; }
    int key = pass ? s : d;
    atomicAdd(&lbase[key >> BSH], 1);
  }
  __syncthreads();
  if (tid < 64) {                      // wave-0 exclusive scan over K counts
    int carry = 0;
    for (int c0 = 0; c0 < K; c0 += 64) {
      int c = c0 + tid;
      int v = (c < K) ? lbase[c] : 0;
      int inc = v;
      #pragma unroll
      for (int o = 1; o < 64; o <<= 1) {
        int u = __shfl_up(inc, o, 64);
        if (tid >= o) inc += u;
      }
      if (c < K) lbase[c] = inc - v + carry;
      carry += __shfl(inc, 63, 64);
    }
  }
  __syncthreads();
  for (int k = tid; k < K; k += 256) {
    lcur[k] = lbase[k];
    gbase[k] = off[k] + hist[(size_t)k * B + bid];
  }
  __syncthreads();
  for (int i = base + tid; i < lim; i += 256) {
    int s, d;
    if (i < E) { s = src[i]; d = dst[i]; } else { s = d = i - E; }
    int key = pass ? s : d;
    int val = pass ? d : s;
    int pos = atomicAdd(&lcur[key >> BSH], 1);
    stage[pos] = (unsigned int)val | ((unsigned int)key << 16);
  }
  __syncthreads();
  for (int i = tid; i < cnt; i += 256) {
    unsigned int wv = stage[i];
    int k = wv >> (16 + BSH);
    out[gbase[k] + (i - lbase[k])] = wv;
  }
}

// per-bucket key-sort in LDS -> csr (coalesced write) + row pointers; both passes
__global__ __launch_bounds__(256) void bucket_csr2(
    const unsigned int* __restrict__ partA, const int* __restrict__ offA, int KA, int NA,
    const unsigned int* __restrict__ partB, const int* __restrict__ offB, int KB, int NB,
    int E2, int* __restrict__ csrA, int* __restrict__ rowA,
    int* __restrict__ csrB, int* __restrict__ rowB)
{
  __shared__ int sbuf[CAP];        // 32 KB
  __shared__ int hist[BW + 1];
  __shared__ int cur[BW];
  const unsigned int* part; const int* off; int* csr; int* row; int k, K, N;
  if ((int)blockIdx.x < KA) { k = blockIdx.x; part = partA; off = offA; csr = csrA; row = rowA; K = KA; N = NA; }
  else { k = blockIdx.x - KA; part = partB; off = offB; csr = csrB; row = rowB; K = KB; N = NB; }
  int tid = threadIdx.x;
  int beg = off[k], end = off[k + 1];
  int d0 = k << BSH;
  int width = (BW < N - d0) ? BW : (N - d0);
  int cnt = end - beg;

  for (int i = tid; i <= BW; i += 256) hist[i] = 0;
  __syncthreads();
  for (int i = tid; i < cnt; i += 256)
    atomicAdd(&hist[(part[beg + i] >> 16) & (BW - 1)], 1);
  __syncthreads();
  if (tid == 0) {
    int run = 0;
    for (int j = 0; j < width; ++j) { int c = hist[j]; hist[j] = run; run += c; }
    hist[width] = run;
  }
  __syncthreads();
  if (tid < width) { cur[tid] = hist[tid]; row[d0 + tid] = beg + hist[tid]; }
  if (k == K - 1 && tid == 0) row[N] = E2;
  __syncthreads();
  if (cnt <= CAP) {
    for (int i = tid; i < cnt; i += 256) {
      unsigned int wv = part[beg + i];
      int pos = atomicAdd(&cur[(wv >> 16) & (BW - 1)], 1);
      sbuf[pos] = wv & 0xFFFF;
    }
    __syncthreads();
    for (int i = tid; i < cnt; i += 256) csr[beg + i] = sbuf[i];
  } else {
    for (int i = tid; i < cnt; i += 256) {   // fallback, never for uniform data
      unsigned int wv = part[beg + i];
      int pos = atomicAdd(&cur[(wv >> 16) & (BW - 1)], 1);
      csr[beg + pos] = wv & 0xFFFF;
    }
  }
}

// ---------------- message stage ----------------
__device__ __forceinline__ float lrelu_clamp(float a) {
  a = (a > 0.f) ? a : 0.2f * a;
  return fminf(a, 43.f);
}

// csr_message4: half-wave per dst (2 dsts/wave), 2 channels per lane.
// Per 32-edge tile each lane computes one edge's (e0,e1) once, deposits
// sv/e0/e1 in a per-wave LDS strip; inner loop broadcasts via ds_read
// at immediate offsets (no readlane/cndmask), loads one bf16 PAIR per
// lane (global_load_dword), unpacks with shift/and, 2 fmacs.
// ~5 VALU + 2 DS + 1 VMEM per wave-iteration retiring 2 edges x 64 ch.
__global__ __launch_bounds__(256) void csr_message4(
    const int* __restrict__ rowA, const int* __restrict__ csrA,
    const float* __restrict__ lsA, const float* __restrict__ ldA,
    const __hip_bfloat16* __restrict__ xsA, float* __restrict__ outA, int NdA,
    const int* __restrict__ rowB, const int* __restrict__ csrB,
    const float* __restrict__ lsB, const float* __restrict__ ldB,
    const __hip_bfloat16* __restrict__ xsB, float* __restrict__ outB, int NdB,
    const float* __restrict__ bias, int blocksA)
{
  const int* row; const int* csr_src; const float* logit_s; const float* logit_d;
  const __hip_bfloat16* xs; float* out; int Nd, blk;
  if ((int)blockIdx.x < blocksA) { row = rowA; csr_src = csrA; logit_s = lsA; logit_d = ldA; xs = xsA; out = outA; Nd = NdA; blk = blockIdx.x; }
  else { row = rowB; csr_src = csrB; logit_s = lsB; logit_d = ldB; xs = xsB; out = outB; Nd = NdB; blk = blockIdx.x - blocksA; }

  __shared__ int lds[4 * 192];     // per wave: [0..63]=sv, [64..127]=e0, [128..191]=e1
  int tid  = threadIdx.x;
  int wid  = tid >> 6;
  int lane = tid & 63;
  int l31  = lane & 31;
  int half = lane >> 5;

  int* L = &lds[wid * 192];
  float* Lf = (float*)L;
  const int*   svp = L + (lane & 32);                              // sv of my half, slot j
  const float* wp  = Lf + 64 + ((l31 & 16) << 2) + (lane & 32);    // e(head) of my half, slot j
  const unsigned*  xs2 = (const unsigned*)xs;                      // bf16 pair per dword
  const float2* ls2 = (const float2*)logit_s;

  int d = blk * 8 + (wid << 1) + half;
  int beg = 0, end = 0;
  float2 ld2 = {0.f, 0.f};
  if (d < Nd) {
    beg = row[d]; end = row[d + 1];
    ld2 = ((const float2*)logit_d)[d];
  }

  int nt = ((end - beg) + 31) >> 5;
  nt = max(nt, __shfl_xor(nt, 32, 64));      // wave-uniform tile count

  float2 accA = {0.f, 0.f}, accB = {0.f, 0.f};
  float s0 = 0.f, s1 = 0.f;
  int myPos = beg;

#define EDGE_STEP(J, ACC) {                                        \
    int   svj = svp[(J)];                                          \
    float wj  = wp[(J)];                                           \
    unsigned xv = xs2[svj * 32 + l31];                             \
    ACC.x = fmaf(wj, __uint_as_float(xv << 16), ACC.x);            \
    ACC.y = fmaf(wj, __uint_as_float(xv & 0xffff0000u), ACC.y);    \
  }

  for (int tile = 0; tile < nt; ++tile, myPos += 32) {
    int tc = end - myPos; tc = tc < 0 ? 0 : (tc > 32 ? 32 : tc);
    int sv = 0; float e0 = 0.f, e1 = 0.f;
    if (l31 < tc) {
      sv = csr_src[myPos + l31];
      float2 l2 = ls2[sv];
      e0 = exp2f(lrelu_clamp(l2.x + ld2.x));
      e1 = exp2f(lrelu_clamp(l2.y + ld2.y));
    }
    s0 += e0; s1 += e1;
    L[lane] = sv;
    Lf[64 + lane]  = e0;
    Lf[128 + lane] = e1;
    // same-wave LDS RAW: DS ops are in-order per wave; drain before reads
    asm volatile("s_waitcnt lgkmcnt(0)" ::: "memory");
    int tcmax = max(tc, __shfl_xor(tc, 32, 64));
    int j = 0;
    for (; j + 4 <= tcmax; j += 4) {
      EDGE_STEP(j,     accA)
      EDGE_STEP(j + 1, accB)
      EDGE_STEP(j + 2, accA)
      EDGE_STEP(j + 3, accB)
    }
    for (; j < tcmax; ++j) EDGE_STEP(j, accA)
  }
#undef EDGE_STEP

  // denominators: reduce within each 32-lane half
  #pragma unroll
  for (int off = 16; off > 0; off >>= 1) {
    s0 += __shfl_xor(s0, off, 64);
    s1 += __shfl_xor(s1, off, 64);
  }
  float sD = (l31 & 16) ? s1 : s0;
  float inv = 1.f / (sD + 1e-16f);

  if (d < Nd) {
    float2 b2 = ((const float2*)bias)[l31];
    float2 o;
    o.x = (accA.x + accB.x) * inv + b2.x;
    o.y = (accA.y + accB.y) * inv + b2.y;
    ((float2*)out)[(size_t)d * 32 + l31] = o;
  }
}

extern "C" void kernel_launch(void* const* d_in, const int* in_sizes, int n_in,
                              void* d_out, int out_size, void* d_ws, size_t ws_size,
                              hipStream_t stream)
{
  const float* h_x   = (const float*)d_in[0];
  const float* t_x   = (const float*)d_in[1];
  const int*   edge  = (const int*)d_in[2];
  const float* W_src = (const float*)d_in[3];
  const float* W_dst = (const float*)d_in[4];
  const float* att_s = (const float*)d_in[5];
  const float* att_d = (const float*)d_in[6];
  const float* bias  = (const float*)d_in[7];

  int NH = in_sizes[0] / DD;
  int NT = in_sizes[1] / DD;
  int E  = in_sizes[2] / 2;
  int NL = (NH < NT) ? NH : NT;
  int E2 = E + NL;
  const int* srcA = edge;       // row 0 (h index)
  const int* dstA = edge + E;   // row 1 (t index)

  int KA = (NT + BW - 1) >> BSH;   // pass A buckets (over t / dst)
  int KB = (NH + BW - 1) >> BSH;   // pass B buckets (over h / src)
  int B  = (E2 + CHUNK - 1) / CHUNK;

  char* w = (char*)d_ws;
  size_t used = 0;
  auto alloc = [&](size_t bytes) {
    char* p = w + used; used = (used + bytes + 255) & ~(size_t)255; return p;
  };
  __hip_bfloat16* xsA = (__hip_bfloat16*)alloc((size_t)NH * HC * 2);
  __hip_bfloat16* xsB = (__hip_bfloat16*)alloc((size_t)NT * HC * 2);
  float* lsA  = (float*)alloc((size_t)NH * 2 * 4);
  float* ldB  = (float*)alloc((size_t)NH * 2 * 4);
  float* lsB  = (float*)alloc((size_t)NT * 2 * 4);
  float* ldA  = (float*)alloc((size_t)NT * 2 * 4);
  int* histA  = (int*)alloc((size_t)KA * B * 4);
  int* histB  = (int*)alloc((size_t)KB * B * 4);
  int* totals = (int*)alloc((size_t)(KA + KB) * 4);
  int* offA   = (int*)alloc((size_t)(KA + 1) * 4);
  int* offB   = (int*)alloc((size_t)(KB + 1) * 4);
  int* rowT   = (int*)alloc((size_t)(NT + 1) * 4);
  int* rowH   = (int*)alloc((size_t)(NH + 1) * 4);
  unsigned int* partA = (unsigned int*)alloc((size_t)E2 * 4);
  unsigned int* partB = (unsigned int*)alloc((size_t)E2 * 4);
  int* csrT   = (int*)alloc((size_t)E2 * 4);
  int* csrH   = (int*)alloc((size_t)E2 * 4);

  float* out   = (float*)d_out;              // (h_rep [NH,64], t_rep [NT,64])
  float* out_h = out;
  float* out_t = out + (size_t)NH * HC;

  int bH = (NH + NPB - 1) / NPB, bT = (NT + NPB - 1) / NPB;
  node_transform2<<<bH + bT, 256, 0, stream>>>(
      h_x, t_x, W_src, W_dst, att_s, att_d,
      xsA, xsB, lsA, ldB, lsB, ldA, NH, NT, bH);

  hist_both<<<B, 256, 0, stream>>>(srcA, dstA, E, NL, histA, histB, KA, KB, B);
  scan_hist<<<(KA + KB + 3) / 4, 256, 0, stream>>>(histA, KA, histB, KB, B, totals);
  scan_totals<<<1, 1024, 0, stream>>>(totals, KA, KB, E2, offA, offB);
  partition_edges<<<dim3(B, 2), 256, 0, stream>>>(
      srcA, dstA, E, NL, histA, offA, histB, offB, partA, partB, KA, KB, B);
  bucket_csr2<<<KA + KB, 256, 0, stream>>>(partA, offA, KA, NT, partB, offB, KB, NH,
                                           E2, csrT, rowT, csrH, rowH);

  // pass A: src=h, dst=t -> t_rep ; pass B: src=t, dst=h -> h_rep
  // 8 dsts per block (4 waves x 2 dsts/wave)
  int gA = (NT + 7) / 8, gB = (NH + 7) / 8;
  csr_message4<<<gA + gB, 256, 0, stream>>>(
      rowT, csrT, lsA, ldA, xsA, out_t, NT,
      rowH, csrH, lsB, ldB, xsB, out_h, NH, bias, gA);
}

// Round 2
// 247.346 us; speedup vs baseline: 1.2982x; 1.1413x over previous
//
#include <hip/hip_runtime.h>
#include <hip/hip_bf16.h>
#include <math.h>

#define HC 64
#define DD 128
#define BSH 7       // bucket = 128 consecutive ids
#define BW  128
#define KMAX 512    // max buckets; ids must fit 16 bits (N <= 65536)
#define CHUNK 4096  // edges per partition/hist workgroup
#define CAP 8192    // LDS sort capacity in bucket_csr (entries)

typedef __attribute__((ext_vector_type(8))) short bf16x8;
typedef __attribute__((ext_vector_type(4))) float f32x4;

// round-to-nearest-even f32 -> bf16 bits (inputs finite)
__device__ __forceinline__ unsigned short f2bf(float f) {
  unsigned u = __float_as_uint(f);
  return (unsigned short)((u + 0x7fffu + ((u >> 16) & 1u)) >> 16);
}

// ---------------- build folded B matrix [80][128] bf16 ----------------
// cols (rows of Bt) 0..63 : Wsrc^T
// 64: sum_c Wsrc[k][ 0+c]*att_src[ 0+c]*LOG2E   (ls head0)
// 65: sum_c Wsrc[k][32+c]*att_src[32+c]*LOG2E   (ls head1)
// 66: sum_c Wdst[k][ 0+c]*att_dst[ 0+c]*LOG2E   (ld head0)
// 67: sum_c Wdst[k][32+c]*att_dst[32+c]*LOG2E   (ld head1)
// 68..79: zero pad (5 MFMA col-tiles of 16)
__global__ __launch_bounds__(128) void build_bt(
    const float* __restrict__ Wsrc, const float* __restrict__ Wdst,
    const float* __restrict__ att_src, const float* __restrict__ att_dst,
    unsigned short* __restrict__ Bt)
{
  int j = blockIdx.x;      // 0..79
  int k = threadIdx.x;     // 0..127
  const float LOG2E = 1.44269504f;
  float v = 0.f;
  if (j < 64) {
    v = Wsrc[k * HC + j];
  } else if (j < 68) {
    int hh = j - 64;
    const float* W = (hh < 2) ? Wsrc : Wdst;
    const float* a = (hh < 2) ? att_src : att_dst;
    int h = hh & 1;
    float s = 0.f;
    for (int c = 0; c < 32; ++c)
      s = fmaf(W[k * HC + h * 32 + c], a[h * 32 + c], s);
    v = s * LOG2E;
  }
  Bt[j * DD + k] = f2bf(v);
}

// ---------------- node transform via MFMA (both graphs, one grid) ------
// one wave = 16 nodes. A = elu(x) split hi/lo bf16 (error ~= W rounding only).
// A frag: row = lane&15, k = (lane>>4)*8 + i  -> 2 global dwordx4 per k-tile
// B frag: col = lane&15, k = (lane>>4)*8 + i  -> 16B load from Bt (L1-hit)
// C/D   : col = lane&15, row = (lane>>4)*4 + r
// acc tiles ct=0..3 -> xs cols; ct=4 cols 0..3 -> [ls_h0, ls_h1, ld_h0, ld_h1]
__global__ __launch_bounds__(256) void node_mfma(
    const float* __restrict__ xH, const float* __restrict__ xT,
    const unsigned short* __restrict__ Bt,
    __hip_bfloat16* __restrict__ xsH, __hip_bfloat16* __restrict__ xsT,
    float* __restrict__ lsH, float* __restrict__ ldH,
    float* __restrict__ lsT, float* __restrict__ ldT,
    int NH, int NT, int blocksH)
{
  const float* x; __hip_bfloat16* xs; float* logit_s; float* logit_d; int N, blk;
  if ((int)blockIdx.x < blocksH) { x = xH; xs = xsH; logit_s = lsH; logit_d = ldH; N = NH; blk = blockIdx.x; }
  else { x = xT; xs = xsT; logit_s = lsT; logit_d = ldT; N = NT; blk = blockIdx.x - blocksH; }

  int tid  = threadIdx.x;
  int wid  = tid >> 6;
  int lane = tid & 63;
  int m    = lane & 15;          // A row / D col index
  int kg   = lane >> 4;          // k-group 0..3
  int nbase = (blk * 4 + wid) * 16;
  if (nbase >= N) return;
  int nrow = nbase + m;
  int nclamp = (nrow < N) ? nrow : (N - 1);

  // ---- load A (4 k-tiles x 8 f32), elu, hi/lo bf16 split ----
  bf16x8 ahi[4], alo[4];
  const float* xrow = x + (size_t)nclamp * DD + kg * 8;
  #pragma unroll
  for (int kt = 0; kt < 4; ++kt) {
    float4 v0 = *(const float4*)(xrow + kt * 32);
    float4 v1 = *(const float4*)(xrow + kt * 32 + 4);
    float vv[8] = {v0.x, v0.y, v0.z, v0.w, v1.x, v1.y, v1.z, v1.w};
    #pragma unroll
    for (int i = 0; i < 8; ++i) {
      float v = vv[i];
      v = (v > 0.f) ? v : (exp2f(v * 1.44269504f) - 1.f);   // elu
      unsigned hb = __float_as_uint(v) & 0xffff0000u;       // truncate -> hi
      ahi[kt][i] = (short)(hb >> 16);
      alo[kt][i] = (short)f2bf(v - __uint_as_float(hb));    // exact residual, RNE
    }
  }

  // ---- MFMA: 5 col-tiles x 4 k-tiles x (hi+lo) ----
  f32x4 acc[5];
  #pragma unroll
  for (int ct = 0; ct < 5; ++ct) acc[ct] = (f32x4){0.f, 0.f, 0.f, 0.f};
  const unsigned short* bbase = Bt + m * DD + kg * 8;   // + ct*16*DD + kt*32
  #pragma unroll
  for (int ct = 0; ct < 5; ++ct) {
    #pragma unroll
    for (int kt = 0; kt < 4; ++kt) {
      bf16x8 b = *(const bf16x8*)(bbase + ct * 16 * DD + kt * 32);
      acc[ct] = __builtin_amdgcn_mfma_f32_16x16x32_bf16(ahi[kt], b, acc[ct], 0, 0, 0);
      acc[ct] = __builtin_amdgcn_mfma_f32_16x16x32_bf16(alo[kt], b, acc[ct], 0, 0, 0);
    }
  }

  // ---- epilogue ----
  int r0 = kg * 4;
  unsigned short* xsu = (unsigned short*)xs;
  #pragma unroll
  for (int ct = 0; ct < 4; ++ct) {
    #pragma unroll
    for (int r = 0; r < 4; ++r) {
      int n = nbase + r0 + r;
      if (n < N) xsu[(size_t)n * HC + ct * 16 + m] = f2bf(acc[ct][r]);
    }
  }
  if (m < 4) {
    float* dst = (m < 2) ? logit_s : logit_d;
    int h = m & 1;
    #pragma unroll
    for (int r = 0; r < 4; ++r) {
      int n = nbase + r0 + r;
      if (n < N) dst[n * 2 + h] = acc[4][r];
    }
  }
}

// ---------------- counting sort ----------------
__global__ __launch_bounds__(256) void hist_both(
    const int* __restrict__ src, const int* __restrict__ dst, int E, int NL,
    int* __restrict__ histA, int* __restrict__ histB, int KA, int KB, int B)
{
  __shared__ int hA[KMAX];
  __shared__ int hB[KMAX];
  int tid = threadIdx.x, bid = blockIdx.x;
  for (int i = tid; i < KA; i += 256) hA[i] = 0;
  for (int i = tid; i < KB; i += 256) hB[i] = 0;
  __syncthreads();
  int base = bid * CHUNK;
  int E2 = E + NL;
  int lim = base + CHUNK < E2 ? base + CHUNK : E2;
  for (int i = base + tid; i < lim; i += 256) {
    int s, d;
    if (i < E) { s = src[i]; d = dst[i]; } else { s = d = i - E; }
    atomicAdd(&hA[d >> BSH], 1);
    atomicAdd(&hB[s >> BSH], 1);
  }
  __syncthreads();
  for (int k = tid; k < KA; k += 256) histA[(size_t)k * B + bid] = hA[k];
  for (int k = tid; k < KB; k += 256) histB[(size_t)k * B + bid] = hB[k];
}

// one WAVE per bucket: exclusive scan of its B chunk counts; emit totals
__global__ __launch_bounds__(256) void scan_hist(
    int* __restrict__ histA, int KA, int* __restrict__ histB, int KB, int B,
    int* __restrict__ totals)
{
  int j = blockIdx.x * 4 + (threadIdx.x >> 6);
  if (j >= KA + KB) return;
  int lane = threadIdx.x & 63;
  int* rowp = (j < KA) ? &histA[(size_t)j * B] : &histB[(size_t)(j - KA) * B];
  int carry = 0;
  for (int c0 = 0; c0 < B; c0 += 64) {
    int c = c0 + lane;
    int v = (c < B) ? rowp[c] : 0;
    int inc = v;
    #pragma unroll
    for (int off = 1; off < 64; off <<= 1) {
      int u = __shfl_up(inc, off, 64);
      if (lane >= off) inc += u;
    }
    if (c < B) rowp[c] = inc - v + carry;
    carry += __shfl(inc, 63, 64);
  }
  if (lane == 0) totals[j] = carry;
}

__global__ __launch_bounds__(1024) void scan_totals(
    const int* __restrict__ totals, int KA, int KB, int E2,
    int* __restrict__ offA, int* __restrict__ offB)
{
  __shared__ int buf[1024];
  int t = threadIdx.x;
  int v = (t < KA) ? totals[t] : 0;
  buf[t] = v; __syncthreads();
  #pragma unroll
  for (int off = 1; off < 1024; off <<= 1) {
    int u = (t >= off) ? buf[t - off] : 0;
    __syncthreads(); buf[t] += u; __syncthreads();
  }
  if (t < KA) offA[t] = buf[t] - v;
  if (t == 0) offA[KA] = E2;
  __syncthreads();
  int v2 = (t < KB) ? totals[KA + t] : 0;
  buf[t] = v2; __syncthreads();
  #pragma unroll
  for (int off = 1; off < 1024; off <<= 1) {
    int u = (t >= off) ? buf[t - off] : 0;
    __syncthreads(); buf[t] += u; __syncthreads();
  }
  if (t < KB) offB[t] = buf[t] - v2;
  if (t == 0) offB[KB] = E2;
}

// partition into bucket-contiguous segments. word = other | (key << 16);
// bucket recovered as w >> (16+BSH) (no search). blockIdx.y selects pass.
__global__ __launch_bounds__(256) void partition_edges(
    const int* __restrict__ src, const int* __restrict__ dst, int E, int NL,
    const int* __restrict__ histA, const int* __restrict__ offA,
    const int* __restrict__ histB, const int* __restrict__ offB,
    unsigned int* __restrict__ partA, unsigned int* __restrict__ partB,
    int KA, int KB, int B)
{
  __shared__ unsigned int stage[CHUNK];  // 16 KB
  __shared__ int lbase[KMAX];
  __shared__ int lcur[KMAX];
  __shared__ int gbase[KMAX];
  int tid = threadIdx.x, bid = blockIdx.x;
  int pass = blockIdx.y;
  const int K = pass ? KB : KA;
  const int* hist = pass ? histB : histA;
  const int* off  = pass ? offB : offA;
  unsigned int* out = pass ? partB : partA;

  int base = bid * CHUNK;
  int E2 = E + NL;
  int lim = base + CHUNK < E2 ? base + CHUNK : E2;
  int cnt = lim - base;

  for (int i = tid; i < K; i += 256) lbase[i] = 0;
  __syncthreads();
  for (int i = base + tid; i < lim; i += 256) {
    int s, d;
    if (i < E) { s = src[i]; d = dst[i]; } else { s = d = i - E; }
    int key = pass ? s : d;
    atomicAdd(&lbase[key >> BSH], 1);
  }
  __syncthreads();
  if (tid < 64) {                      // wave-0 exclusive scan over K counts
    int carry = 0;
    for (int c0 = 0; c0 < K; c0 += 64) {
      int c = c0 + tid;
      int v = (c < K) ? lbase[c] : 0;
      int inc = v;
      #pragma unroll
      for (int o = 1; o < 64; o <<= 1) {
        int u = __shfl_up(inc, o, 64);
        if (tid >= o) inc += u;
      }
      if (c < K) lbase[c] = inc - v + carry;
      carry += __shfl(inc, 63, 64);
    }
  }
  __syncthreads();
  for (int k = tid; k < K; k += 256) {
    lcur[k] = lbase[k];
    gbase[k] = off[k] + hist[(size_t)k * B + bid];
  }
  __syncthreads();
  for (int i = base + tid; i < lim; i += 256) {
    int s, d;
    if (i < E) { s = src[i]; d = dst[i]; } else { s = d = i - E; }
    int key = pass ? s : d;
    int val = pass ? d : s;
    int pos = atomicAdd(&lcur[key >> BSH], 1);
    stage[pos] = (unsigned int)val | ((unsigned int)key << 16);
  }
  __syncthreads();
  for (int i = tid; i < cnt; i += 256) {
    unsigned int wv = stage[i];
    int k = wv >> (16 + BSH);
    out[gbase[k] + (i - lbase[k])] = wv;
  }
}

// per-bucket key-sort in LDS -> csr (coalesced write) + row pointers; both passes
__global__ __launch_bounds__(256) void bucket_csr2(
    const unsigned int* __restrict__ partA, const int* __restrict__ offA, int KA, int NA,
    const unsigned int* __restrict__ partB, const int* __restrict__ offB, int KB, int NB,
    int E2, int* __restrict__ csrA, int* __restrict__ rowA,
    int* __restrict__ csrB, int* __restrict__ rowB)
{
  __shared__ int sbuf[CAP];        // 32 KB
  __shared__ int hist[BW + 1];
  __shared__ int cur[BW];
  const unsigned int* part; const int* off; int* csr; int* row; int k, K, N;
  if ((int)blockIdx.x < KA) { k = blockIdx.x; part = partA; off = offA; csr = csrA; row = rowA; K = KA; N = NA; }
  else { k = blockIdx.x - KA; part = partB; off = offB; csr = csrB; row = rowB; K = KB; N = NB; }
  int tid = threadIdx.x;
  int beg = off[k], end = off[k + 1];
  int d0 = k << BSH;
  int width = (BW < N - d0) ? BW : (N - d0);
  int cnt = end - beg;

  for (int i = tid; i <= BW; i += 256) hist[i] = 0;
  __syncthreads();
  for (int i = tid; i < cnt; i += 256)
    atomicAdd(&hist[(part[beg + i] >> 16) & (BW - 1)], 1);
  __syncthreads();
  if (tid == 0) {
    int run = 0;
    for (int j = 0; j < width; ++j) { int c = hist[j]; hist[j] = run; run += c; }
    hist[width] = run;
  }
  __syncthreads();
  if (tid < width) { cur[tid] = hist[tid]; row[d0 + tid] = beg + hist[tid]; }
  if (k == K - 1 && tid == 0) row[N] = E2;
  __syncthreads();
  if (cnt <= CAP) {
    for (int i = tid; i < cnt; i += 256) {
      unsigned int wv = part[beg + i];
      int pos = atomicAdd(&cur[(wv >> 16) & (BW - 1)], 1);
      sbuf[pos] = wv & 0xFFFF;
    }
    __syncthreads();
    for (int i = tid; i < cnt; i += 256) csr[beg + i] = sbuf[i];
  } else {
    for (int i = tid; i < cnt; i += 256) {   // fallback, never for uniform data
      unsigned int wv = part[beg + i];
      int pos = atomicAdd(&cur[(wv >> 16) & (BW - 1)], 1);
      csr[beg + pos] = wv & 0xFFFF;
    }
  }
}

// ---------------- message stage ----------------
__device__ __forceinline__ float lrelu_clamp(float a) {
  a = (a > 0.f) ? a : 0.2f * a;
  return fminf(a, 43.f);
}

// csr_message4: half-wave per dst (2 dsts/wave), 2 channels per lane.
__global__ __launch_bounds__(256) void csr_message4(
    const int* __restrict__ rowA, const int* __restrict__ csrA,
    const float* __restrict__ lsA, const float* __restrict__ ldA,
    const __hip_bfloat16* __restrict__ xsA, float* __restrict__ outA, int NdA,
    const int* __restrict__ rowB, const int* __restrict__ csrB,
    const float* __restrict__ lsB, const float* __restrict__ ldB,
    const __hip_bfloat16* __restrict__ xsB, float* __restrict__ outB, int NdB,
    const float* __restrict__ bias, int blocksA)
{
  const int* row; const int* csr_src; const float* logit_s; const float* logit_d;
  const __hip_bfloat16* xs; float* out; int Nd, blk;
  if ((int)blockIdx.x < blocksA) { row = rowA; csr_src = csrA; logit_s = lsA; logit_d = ldA; xs = xsA; out = outA; Nd = NdA; blk = blockIdx.x; }
  else { row = rowB; csr_src = csrB; logit_s = lsB; logit_d = ldB; xs = xsB; out = outB; Nd = NdB; blk = blockIdx.x - blocksA; }

  __shared__ int lds[4 * 192];     // per wave: [0..63]=sv, [64..127]=e0, [128..191]=e1
  int tid  = threadIdx.x;
  int wid  = tid >> 6;
  int lane = tid & 63;
  int l31  = lane & 31;
  int half = lane >> 5;

  int* L = &lds[wid * 192];
  float* Lf = (float*)L;
  const int*   svp = L + (lane & 32);                              // sv of my half, slot j
  const float* wp  = Lf + 64 + ((l31 & 16) << 2) + (lane & 32);    // e(head) of my half, slot j
  const unsigned*  xs2 = (const unsigned*)xs;                      // bf16 pair per dword
  const float2* ls2 = (const float2*)logit_s;

  int d = blk * 8 + (wid << 1) + half;
  int beg = 0, end = 0;
  float2 ld2 = {0.f, 0.f};
  if (d < Nd) {
    beg = row[d]; end = row[d + 1];
    ld2 = ((const float2*)logit_d)[d];
  }

  int nt = ((end - beg) + 31) >> 5;
  nt = max(nt, __shfl_xor(nt, 32, 64));      // wave-uniform tile count

  float2 accA = {0.f, 0.f}, accB = {0.f, 0.f};
  float s0 = 0.f, s1 = 0.f;
  int myPos = beg;

#define EDGE_STEP(J, ACC) {                                        \
    int   svj = svp[(J)];                                          \
    float wj  = wp[(J)];                                           \
    unsigned xv = xs2[svj * 32 + l31];                             \
    ACC.x = fmaf(wj, __uint_as_float(xv << 16), ACC.x);            \
    ACC.y = fmaf(wj, __uint_as_float(xv & 0xffff0000u), ACC.y);    \
  }

  for (int tile = 0; tile < nt; ++tile, myPos += 32) {
    int tc = end - myPos; tc = tc < 0 ? 0 : (tc > 32 ? 32 : tc);
    int sv = 0; float e0 = 0.f, e1 = 0.f;
    if (l31 < tc) {
      sv = csr_src[myPos + l31];
      float2 l2 = ls2[sv];
      e0 = exp2f(lrelu_clamp(l2.x + ld2.x));
      e1 = exp2f(lrelu_clamp(l2.y + ld2.y));
    }
    s0 += e0; s1 += e1;
    L[lane] = sv;
    Lf[64 + lane]  = e0;
    Lf[128 + lane] = e1;
    // same-wave LDS RAW: DS ops are in-order per wave; drain before reads
    asm volatile("s_waitcnt lgkmcnt(0)" ::: "memory");
    int tcmax = max(tc, __shfl_xor(tc, 32, 64));
    int j = 0;
    for (; j + 4 <= tcmax; j += 4) {
      EDGE_STEP(j,     accA)
      EDGE_STEP(j + 1, accB)
      EDGE_STEP(j + 2, accA)
      EDGE_STEP(j + 3, accB)
    }
    for (; j < tcmax; ++j) EDGE_STEP(j, accA)
  }
#undef EDGE_STEP

  // denominators: reduce within each 32-lane half
  #pragma unroll
  for (int off = 16; off > 0; off >>= 1) {
    s0 += __shfl_xor(s0, off, 64);
    s1 += __shfl_xor(s1, off, 64);
  }
  float sD = (l31 & 16) ? s1 : s0;
  float inv = 1.f / (sD + 1e-16f);

  if (d < Nd) {
    float2 b2 = ((const float2*)bias)[l31];
    float2 o;
    o.x = (accA.x + accB.x) * inv + b2.x;
    o.y = (accA.y + accB.y) * inv + b2.y;
    ((float2*)out)[(size_t)d * 32 + l31] = o;
  }
}

extern "C" void kernel_launch(void* const* d_in, const int* in_sizes, int n_in,
                              void* d_out, int out_size, void* d_ws, size_t ws_size,
                              hipStream_t stream)
{
  const float* h_x   = (const float*)d_in[0];
  const float* t_x   = (const float*)d_in[1];
  const int*   edge  = (const int*)d_in[2];
  const float* W_src = (const float*)d_in[3];
  const float* W_dst = (const float*)d_in[4];
  const float* att_s = (const float*)d_in[5];
  const float* att_d = (const float*)d_in[6];
  const float* bias  = (const float*)d_in[7];

  int NH = in_sizes[0] / DD;
  int NT = in_sizes[1] / DD;
  int E  = in_sizes[2] / 2;
  int NL = (NH < NT) ? NH : NT;
  int E2 = E + NL;
  const int* srcA = edge;       // row 0 (h index)
  const int* dstA = edge + E;   // row 1 (t index)

  int KA = (NT + BW - 1) >> BSH;   // pass A buckets (over t / dst)
  int KB = (NH + BW - 1) >> BSH;   // pass B buckets (over h / src)
  int B  = (E2 + CHUNK - 1) / CHUNK;

  char* w = (char*)d_ws;
  size_t used = 0;
  auto alloc = [&](size_t bytes) {
    char* p = w + used; used = (used + bytes + 255) & ~(size_t)255; return p;
  };
  __hip_bfloat16* xsA = (__hip_bfloat16*)alloc((size_t)NH * HC * 2);
  __hip_bfloat16* xsB = (__hip_bfloat16*)alloc((size_t)NT * HC * 2);
  float* lsA  = (float*)alloc((size_t)NH * 2 * 4);
  float* ldB  = (float*)alloc((size_t)NH * 2 * 4);
  float* lsB  = (float*)alloc((size_t)NT * 2 * 4);
  float* ldA  = (float*)alloc((size_t)NT * 2 * 4);
  int* histA  = (int*)alloc((size_t)KA * B * 4);
  int* histB  = (int*)alloc((size_t)KB * B * 4);
  int* totals = (int*)alloc((size_t)(KA + KB) * 4);
  int* offA   = (int*)alloc((size_t)(KA + 1) * 4);
  int* offB   = (int*)alloc((size_t)(KB + 1) * 4);
  int* rowT   = (int*)alloc((size_t)(NT + 1) * 4);
  int* rowH   = (int*)alloc((size_t)(NH + 1) * 4);
  unsigned int* partA = (unsigned int*)alloc((size_t)E2 * 4);
  unsigned int* partB = (unsigned int*)alloc((size_t)E2 * 4);
  int* csrT   = (int*)alloc((size_t)E2 * 4);
  int* csrH   = (int*)alloc((size_t)E2 * 4);
  unsigned short* Bt = (unsigned short*)alloc((size_t)80 * DD * 2);

  float* out   = (float*)d_out;              // (h_rep [NH,64], t_rep [NT,64])
  float* out_h = out;
  float* out_t = out + (size_t)NH * HC;

  build_bt<<<80, 128, 0, stream>>>(W_src, W_dst, att_s, att_d, Bt);

  int bH = (NH + 63) / 64, bT = (NT + 63) / 64;
  node_mfma<<<bH + bT, 256, 0, stream>>>(
      h_x, t_x, Bt, xsA, xsB, lsA, ldB, lsB, ldA, NH, NT, bH);

  hist_both<<<B, 256, 0, stream>>>(srcA, dstA, E, NL, histA, histB, KA, KB, B);
  scan_hist<<<(KA + KB + 3) / 4, 256, 0, stream>>>(histA, KA, histB, KB, B, totals);
  scan_totals<<<1, 1024, 0, stream>>>(totals, KA, KB, E2, offA, offB);
  partition_edges<<<dim3(B, 2), 256, 0, stream>>>(
      srcA, dstA, E, NL, histA, offA, histB, offB, partA, partB, KA, KB, B);
  bucket_csr2<<<KA + KB, 256, 0, stream>>>(partA, offA, KA, NT, partB, offB, KB, NH,
                                           E2, csrT, rowT, csrH, rowH);

  // pass A: src=h, dst=t -> t_rep ; pass B: src=t, dst=h -> h_rep
  // 8 dsts per block (4 waves x 2 dsts/wave)
  int gA = (NT + 7) / 8, gB = (NH + 7) / 8;
  csr_message4<<<gA + gB, 256, 0, stream>>>(
      rowT, csrT, lsA, ldA, xsA, out_t, NT,
      rowH, csrH, lsB, ldB, xsB, out_h, NH, bias, gA);
}

// Round 3
// 242.849 us; speedup vs baseline: 1.3223x; 1.0185x over previous
//
#include <hip/hip_runtime.h>
#include <hip/hip_bf16.h>
#include <math.h>

#define HC 64
#define DD 128
#define BSH 7       // bucket = 128 consecutive ids
#define BW  128
#define KMAX 512    // max buckets; ids must fit 16 bits (N <= 65536)
#define CHUNK 4096  // edges per partition/hist workgroup
#define CAP 8192    // LDS sort capacity in bucket_csr (entries)

typedef __attribute__((ext_vector_type(8))) short bf16x8;
typedef __attribute__((ext_vector_type(4))) float f32x4;

// round-to-nearest-even f32 -> bf16 bits (inputs finite)
__device__ __forceinline__ unsigned short f2bf(float f) {
  unsigned u = __float_as_uint(f);
  return (unsigned short)((u + 0x7fffu + ((u >> 16) & 1u)) >> 16);
}

// ---------------- build folded B matrix [80][128] bf16 ----------------
// cols (rows of Bt) 0..63 : Wsrc^T
// 64: sum_c Wsrc[k][ 0+c]*att_src[ 0+c]*LOG2E   (ls head0)
// 65: sum_c Wsrc[k][32+c]*att_src[32+c]*LOG2E   (ls head1)
// 66: sum_c Wdst[k][ 0+c]*att_dst[ 0+c]*LOG2E   (ld head0)
// 67: sum_c Wdst[k][32+c]*att_dst[32+c]*LOG2E   (ld head1)
// 68..79: zero pad (5 MFMA col-tiles of 16)
__global__ __launch_bounds__(128) void build_bt(
    const float* __restrict__ Wsrc, const float* __restrict__ Wdst,
    const float* __restrict__ att_src, const float* __restrict__ att_dst,
    unsigned short* __restrict__ Bt)
{
  int j = blockIdx.x;      // 0..79
  int k = threadIdx.x;     // 0..127
  const float LOG2E = 1.44269504f;
  float v = 0.f;
  if (j < 64) {
    v = Wsrc[k * HC + j];
  } else if (j < 68) {
    int hh = j - 64;
    const float* W = (hh < 2) ? Wsrc : Wdst;
    const float* a = (hh < 2) ? att_src : att_dst;
    int h = hh & 1;
    float s = 0.f;
    for (int c = 0; c < 32; ++c)
      s = fmaf(W[k * HC + h * 32 + c], a[h * 32 + c], s);
    v = s * LOG2E;
  }
  Bt[j * DD + k] = f2bf(v);
}

// ---------------- node transform via MFMA (both graphs, one grid) ------
// one wave = 16 nodes. A = elu(x) split hi/lo bf16 (error ~= W rounding only).
__global__ __launch_bounds__(256) void node_mfma(
    const float* __restrict__ xH, const float* __restrict__ xT,
    const unsigned short* __restrict__ Bt,
    __hip_bfloat16* __restrict__ xsH, __hip_bfloat16* __restrict__ xsT,
    float* __restrict__ lsH, float* __restrict__ ldH,
    float* __restrict__ lsT, float* __restrict__ ldT,
    int NH, int NT, int blocksH)
{
  const float* x; __hip_bfloat16* xs; float* logit_s; float* logit_d; int N, blk;
  if ((int)blockIdx.x < blocksH) { x = xH; xs = xsH; logit_s = lsH; logit_d = ldH; N = NH; blk = blockIdx.x; }
  else { x = xT; xs = xsT; logit_s = lsT; logit_d = ldT; N = NT; blk = blockIdx.x - blocksH; }

  int tid  = threadIdx.x;
  int wid  = tid >> 6;
  int lane = tid & 63;
  int m    = lane & 15;          // A row / D col index
  int kg   = lane >> 4;          // k-group 0..3
  int nbase = (blk * 4 + wid) * 16;
  if (nbase >= N) return;
  int nrow = nbase + m;
  int nclamp = (nrow < N) ? nrow : (N - 1);

  // ---- load A (4 k-tiles x 8 f32), elu, hi/lo bf16 split ----
  bf16x8 ahi[4], alo[4];
  const float* xrow = x + (size_t)nclamp * DD + kg * 8;
  #pragma unroll
  for (int kt = 0; kt < 4; ++kt) {
    float4 v0 = *(const float4*)(xrow + kt * 32);
    float4 v1 = *(const float4*)(xrow + kt * 32 + 4);
    float vv[8] = {v0.x, v0.y, v0.z, v0.w, v1.x, v1.y, v1.z, v1.w};
    #pragma unroll
    for (int i = 0; i < 8; ++i) {
      float v = vv[i];
      v = (v > 0.f) ? v : (exp2f(v * 1.44269504f) - 1.f);   // elu
      unsigned hb = __float_as_uint(v) & 0xffff0000u;       // truncate -> hi
      ahi[kt][i] = (short)(hb >> 16);
      alo[kt][i] = (short)f2bf(v - __uint_as_float(hb));    // exact residual, RNE
    }
  }

  // ---- MFMA: 5 col-tiles x 4 k-tiles x (hi+lo) ----
  f32x4 acc[5];
  #pragma unroll
  for (int ct = 0; ct < 5; ++ct) acc[ct] = (f32x4){0.f, 0.f, 0.f, 0.f};
  const unsigned short* bbase = Bt + m * DD + kg * 8;   // + ct*16*DD + kt*32
  #pragma unroll
  for (int ct = 0; ct < 5; ++ct) {
    #pragma unroll
    for (int kt = 0; kt < 4; ++kt) {
      bf16x8 b = *(const bf16x8*)(bbase + ct * 16 * DD + kt * 32);
      acc[ct] = __builtin_amdgcn_mfma_f32_16x16x32_bf16(ahi[kt], b, acc[ct], 0, 0, 0);
      acc[ct] = __builtin_amdgcn_mfma_f32_16x16x32_bf16(alo[kt], b, acc[ct], 0, 0, 0);
    }
  }

  // ---- epilogue ----
  int r0 = kg * 4;
  unsigned short* xsu = (unsigned short*)xs;
  #pragma unroll
  for (int ct = 0; ct < 4; ++ct) {
    #pragma unroll
    for (int r = 0; r < 4; ++r) {
      int n = nbase + r0 + r;
      if (n < N) xsu[(size_t)n * HC + ct * 16 + m] = f2bf(acc[ct][r]);
    }
  }
  if (m < 4) {
    float* dst = (m < 2) ? logit_s : logit_d;
    int h = m & 1;
    #pragma unroll
    for (int r = 0; r < 4; ++r) {
      int n = nbase + r0 + r;
      if (n < N) dst[n * 2 + h] = acc[4][r];
    }
  }
}

// ---------------- counting sort ----------------
__global__ __launch_bounds__(256) void hist_both(
    const int* __restrict__ src, const int* __restrict__ dst, int E, int NL,
    int* __restrict__ histA, int* __restrict__ histB, int KA, int KB, int B)
{
  __shared__ int hA[KMAX];
  __shared__ int hB[KMAX];
  int tid = threadIdx.x, bid = blockIdx.x;
  for (int i = tid; i < KA; i += 256) hA[i] = 0;
  for (int i = tid; i < KB; i += 256) hB[i] = 0;
  __syncthreads();
  int base = bid * CHUNK;
  int E2 = E + NL;
  int lim = base + CHUNK < E2 ? base + CHUNK : E2;
  for (int i = base + tid; i < lim; i += 256) {
    int s, d;
    if (i < E) { s = src[i]; d = dst[i]; } else { s = d = i - E; }
    atomicAdd(&hA[d >> BSH], 1);
    atomicAdd(&hB[s >> BSH], 1);
  }
  __syncthreads();
  for (int k = tid; k < KA; k += 256) histA[(size_t)k * B + bid] = hA[k];
  for (int k = tid; k < KB; k += 256) histB[(size_t)k * B + bid] = hB[k];
}

// one WAVE per bucket: exclusive scan of its B chunk counts; emit totals
__global__ __launch_bounds__(256) void scan_hist(
    int* __restrict__ histA, int KA, int* __restrict__ histB, int KB, int B,
    int* __restrict__ totals)
{
  int j = blockIdx.x * 4 + (threadIdx.x >> 6);
  if (j >= KA + KB) return;
  int lane = threadIdx.x & 63;
  int* rowp = (j < KA) ? &histA[(size_t)j * B] : &histB[(size_t)(j - KA) * B];
  int carry = 0;
  for (int c0 = 0; c0 < B; c0 += 64) {
    int c = c0 + lane;
    int v = (c < B) ? rowp[c] : 0;
    int inc = v;
    #pragma unroll
    for (int off = 1; off < 64; off <<= 1) {
      int u = __shfl_up(inc, off, 64);
      if (lane >= off) inc += u;
    }
    if (c < B) rowp[c] = inc - v + carry;
    carry += __shfl(inc, 63, 64);
  }
  if (lane == 0) totals[j] = carry;
}

__global__ __launch_bounds__(1024) void scan_totals(
    const int* __restrict__ totals, int KA, int KB, int E2,
    int* __restrict__ offA, int* __restrict__ offB)
{
  __shared__ int buf[1024];
  int t = threadIdx.x;
  int v = (t < KA) ? totals[t] : 0;
  buf[t] = v; __syncthreads();
  #pragma unroll
  for (int off = 1; off < 1024; off <<= 1) {
    int u = (t >= off) ? buf[t - off] : 0;
    __syncthreads(); buf[t] += u; __syncthreads();
  }
  if (t < KA) offA[t] = buf[t] - v;
  if (t == 0) offA[KA] = E2;
  __syncthreads();
  int v2 = (t < KB) ? totals[KA + t] : 0;
  buf[t] = v2; __syncthreads();
  #pragma unroll
  for (int off = 1; off < 1024; off <<= 1) {
    int u = (t >= off) ? buf[t - off] : 0;
    __syncthreads(); buf[t] += u; __syncthreads();
  }
  if (t < KB) offB[t] = buf[t] - v2;
  if (t == 0) offB[KB] = E2;
}

// partition into bucket-contiguous segments. word = other | (key << 16);
// bucket recovered as w >> (16+BSH) (no search). blockIdx.y selects pass.
__global__ __launch_bounds__(256) void partition_edges(
    const int* __restrict__ src, const int* __restrict__ dst, int E, int NL,
    const int* __restrict__ histA, const int* __restrict__ offA,
    const int* __restrict__ histB, const int* __restrict__ offB,
    unsigned int* __restrict__ partA, unsigned int* __restrict__ partB,
    int KA, int KB, int B)
{
  __shared__ unsigned int stage[CHUNK];  // 16 KB
  __shared__ int lbase[KMAX];
  __shared__ int lcur[KMAX];
  __shared__ int gbase[KMAX];
  int tid = threadIdx.x, bid = blockIdx.x;
  int pass = blockIdx.y;
  const int K = pass ? KB : KA;
  const int* hist = pass ? histB : histA;
  const int* off  = pass ? offB : offA;
  unsigned int* out = pass ? partB : partA;

  int base = bid * CHUNK;
  int E2 = E + NL;
  int lim = base + CHUNK < E2 ? base + CHUNK : E2;
  int cnt = lim - base;

  for (int i = tid; i < K; i += 256) lbase[i] = 0;
  __syncthreads();
  for (int i = base + tid; i < lim; i += 256) {
    int s, d;
    if (i < E) { s = src[i]; d = dst[i]; } else { s = d = i - E; }
    int key = pass ? s : d;
    atomicAdd(&lbase[key >> BSH], 1);
  }
  __syncthreads();
  if (tid < 64) {                      // wave-0 exclusive scan over K counts
    int carry = 0;
    for (int c0 = 0; c0 < K; c0 += 64) {
      int c = c0 + tid;
      int v = (c < K) ? lbase[c] : 0;
      int inc = v;
      #pragma unroll
      for (int o = 1; o < 64; o <<= 1) {
        int u = __shfl_up(inc, o, 64);
        if (tid >= o) inc += u;
      }
      if (c < K) lbase[c] = inc - v + carry;
      carry += __shfl(inc, 63, 64);
    }
  }
  __syncthreads();
  for (int k = tid; k < K; k += 256) {
    lcur[k] = lbase[k];
    gbase[k] = off[k] + hist[(size_t)k * B + bid];
  }
  __syncthreads();
  for (int i = base + tid; i < lim; i += 256) {
    int s, d;
    if (i < E) { s = src[i]; d = dst[i]; } else { s = d = i - E; }
    int key = pass ? s : d;
    int val = pass ? d : s;
    int pos = atomicAdd(&lcur[key >> BSH], 1);
    stage[pos] = (unsigned int)val | ((unsigned int)key << 16);
  }
  __syncthreads();
  for (int i = tid; i < cnt; i += 256) {
    unsigned int wv = stage[i];
    int k = wv >> (16 + BSH);
    out[gbase[k] + (i - lbase[k])] = wv;
  }
}

// per-bucket key-sort in LDS -> csr (coalesced write) + row pointers; both passes
__global__ __launch_bounds__(256) void bucket_csr2(
    const unsigned int* __restrict__ partA, const int* __restrict__ offA, int KA, int NA,
    const unsigned int* __restrict__ partB, const int* __restrict__ offB, int KB, int NB,
    int E2, int* __restrict__ csrA, int* __restrict__ rowA,
    int* __restrict__ csrB, int* __restrict__ rowB)
{
  __shared__ int sbuf[CAP];        // 32 KB
  __shared__ int hist[BW + 1];
  __shared__ int cur[BW];
  const unsigned int* part; const int* off; int* csr; int* row; int k, K, N;
  if ((int)blockIdx.x < KA) { k = blockIdx.x; part = partA; off = offA; csr = csrA; row = rowA; K = KA; N = NA; }
  else { k = blockIdx.x - KA; part = partB; off = offB; csr = csrB; row = rowB; K = KB; N = NB; }
  int tid = threadIdx.x;
  int beg = off[k], end = off[k + 1];
  int d0 = k << BSH;
  int width = (BW < N - d0) ? BW : (N - d0);
  int cnt = end - beg;

  for (int i = tid; i <= BW; i += 256) hist[i] = 0;
  __syncthreads();
  for (int i = tid; i < cnt; i += 256)
    atomicAdd(&hist[(part[beg + i] >> 16) & (BW - 1)], 1);
  __syncthreads();
  if (tid == 0) {
    int run = 0;
    for (int j = 0; j < width; ++j) { int c = hist[j]; hist[j] = run; run += c; }
    hist[width] = run;
  }
  __syncthreads();
  if (tid < width) { cur[tid] = hist[tid]; row[d0 + tid] = beg + hist[tid]; }
  if (k == K - 1 && tid == 0) row[N] = E2;
  __syncthreads();
  if (cnt <= CAP) {
    for (int i = tid; i < cnt; i += 256) {
      unsigned int wv = part[beg + i];
      int pos = atomicAdd(&cur[(wv >> 16) & (BW - 1)], 1);
      sbuf[pos] = wv & 0xFFFF;
    }
    __syncthreads();
    for (int i = tid; i < cnt; i += 256) csr[beg + i] = sbuf[i];
  } else {
    for (int i = tid; i < cnt; i += 256) {   // fallback, never for uniform data
      unsigned int wv = part[beg + i];
      int pos = atomicAdd(&cur[(wv >> 16) & (BW - 1)], 1);
      csr[beg + pos] = wv & 0xFFFF;
    }
  }
}

// ---------------- message stage ----------------
__device__ __forceinline__ float lrelu_clamp(float a) {
  a = (a > 0.f) ? a : 0.2f * a;
  return fminf(a, 43.f);
}

// csr_message5: half-wave per dst (2 dsts/wave), 2 channels per lane.
// Per 32-edge tile: lane l31 computes edge l31's (sv,e0,e1) once, deposits
// into bank-staggered per-wave LDS arrays (word bases mod 32 = 0/8/16/24
// so quad reads are bank-disjoint). Inner loop reads ONE int4 sv-quad +
// ONE float4 w-quad per 4 edges (ds_read_b128, conflict-free broadcast),
// statically indexed -> 4x fewer LDS instructions, zero conflicts.
// All 32 slots are always written (invalid lanes write 0s) so whole-quad
// processing past tc is exact (adds w=0 terms).
__global__ __launch_bounds__(256) void csr_message5(
    const int* __restrict__ rowA, const int* __restrict__ csrA,
    const float* __restrict__ lsA, const float* __restrict__ ldA,
    const __hip_bfloat16* __restrict__ xsA, float* __restrict__ outA, int NdA,
    const int* __restrict__ rowB, const int* __restrict__ csrB,
    const float* __restrict__ lsB, const float* __restrict__ ldB,
    const __hip_bfloat16* __restrict__ xsB, float* __restrict__ outB, int NdB,
    const float* __restrict__ bias, int blocksA)
{
  const int* row; const int* csr_src; const float* logit_s; const float* logit_d;
  const __hip_bfloat16* xs; float* out; int Nd, blk;
  if ((int)blockIdx.x < blocksA) { row = rowA; csr_src = csrA; logit_s = lsA; logit_d = ldA; xs = xsA; out = outA; Nd = NdA; blk = blockIdx.x; }
  else { row = rowB; csr_src = csrB; logit_s = lsB; logit_d = ldB; xs = xsB; out = outB; Nd = NdB; blk = blockIdx.x - blocksA; }

  // per-wave strip: 232 words. word offsets (base mod 32 in parens):
  //   sv0 @   0 (0)   sv1 @  40 (8)
  //   w00 @  80 (16)  w01 @ 120 (24)   [half0: e0, e1]
  //   w10 @ 160 (0)   w11 @ 200 (8)    [half1: e0, e1]
  __shared__ int lds[4 * 232];     // 3712 B
  int tid  = threadIdx.x;
  int wid  = tid >> 6;
  int lane = tid & 63;
  int l31  = lane & 31;
  int half = lane >> 5;
  int head = l31 >> 4;             // channel group -> attention head

  int* L = &lds[wid * 232];
  float* Lf = (float*)L;
  int sv_w = (half ? 40 : 0) + l31;
  int w0_w = (half ? 160 : 80) + l31;
  int w1_w = (half ? 200 : 120) + l31;
  const int4*   svq = (const int4*)  (L  + (half ? 40 : 0));
  const float4* wq  = (const float4*)(Lf + (half ? (head ? 200 : 160)
                                                 : (head ? 120 : 80)));
  const unsigned* xs2 = (const unsigned*)xs;     // bf16 pair per dword
  const float2* ls2 = (const float2*)logit_s;

  int d = blk * 8 + (wid << 1) + half;
  int beg = 0, end = 0;
  float2 ld2 = {0.f, 0.f};
  if (d < Nd) {
    beg = row[d]; end = row[d + 1];
    ld2 = ((const float2*)logit_d)[d];
  }

  int nt = ((end - beg) + 31) >> 5;
  nt = max(nt, __shfl_xor(nt, 32, 64));      // wave-uniform tile count

  float2 accA = {0.f, 0.f}, accB = {0.f, 0.f};
  float s0 = 0.f, s1 = 0.f;
  int myPos = beg;

#define STEP(SV, W, ACC) {                                         \
    unsigned xv = xs2[(SV) * 32 + l31];                            \
    ACC.x = fmaf((W), __uint_as_float(xv << 16), ACC.x);           \
    ACC.y = fmaf((W), __uint_as_float(xv & 0xffff0000u), ACC.y);   \
  }

  for (int tile = 0; tile < nt; ++tile, myPos += 32) {
    int tc = end - myPos; tc = tc < 0 ? 0 : (tc > 32 ? 32 : tc);
    int sv = 0; float e0 = 0.f, e1 = 0.f;
    if (l31 < tc) {
      sv = csr_src[myPos + l31];
      float2 l2 = ls2[sv];
      e0 = exp2f(lrelu_clamp(l2.x + ld2.x));
      e1 = exp2f(lrelu_clamp(l2.y + ld2.y));
    }
    s0 += e0; s1 += e1;
    L[sv_w]       = sv;
    Lf[w0_w]      = e0;
    Lf[w1_w]      = e1;
    // same-wave cross-lane LDS RAW: DS in-order per wave; this asm is a
    // compiler barrier (no reordering) + drains the writes
    asm volatile("s_waitcnt lgkmcnt(0)" ::: "memory");
    int tcmax = max(tc, __shfl_xor(tc, 32, 64));
    int nq = (tcmax + 3) >> 2;
    for (int q = 0; q < nq; ++q) {
      int4   s4 = svq[q];
      float4 w4 = wq[q];
      STEP(s4.x, w4.x, accA)
      STEP(s4.y, w4.y, accB)
      STEP(s4.z, w4.z, accA)
      STEP(s4.w, w4.w, accB)
    }
  }
#undef STEP

  // denominators: reduce within each 32-lane half
  #pragma unroll
  for (int off = 16; off > 0; off >>= 1) {
    s0 += __shfl_xor(s0, off, 64);
    s1 += __shfl_xor(s1, off, 64);
  }
  float sD = (l31 & 16) ? s1 : s0;
  float inv = 1.f / (sD + 1e-16f);

  if (d < Nd) {
    float2 b2 = ((const float2*)bias)[l31];
    float2 o;
    o.x = (accA.x + accB.x) * inv + b2.x;
    o.y = (accA.y + accB.y) * inv + b2.y;
    ((float2*)out)[(size_t)d * 32 + l31] = o;
  }
}

extern "C" void kernel_launch(void* const* d_in, const int* in_sizes, int n_in,
                              void* d_out, int out_size, void* d_ws, size_t ws_size,
                              hipStream_t stream)
{
  const float* h_x   = (const float*)d_in[0];
  const float* t_x   = (const float*)d_in[1];
  const int*   edge  = (const int*)d_in[2];
  const float* W_src = (const float*)d_in[3];
  const float* W_dst = (const float*)d_in[4];
  const float* att_s = (const float*)d_in[5];
  const float* att_d = (const float*)d_in[6];
  const float* bias  = (const float*)d_in[7];

  int NH = in_sizes[0] / DD;
  int NT = in_sizes[1] / DD;
  int E  = in_sizes[2] / 2;
  int NL = (NH < NT) ? NH : NT;
  int E2 = E + NL;
  const int* srcA = edge;       // row 0 (h index)
  const int* dstA = edge + E;   // row 1 (t index)

  int KA = (NT + BW - 1) >> BSH;   // pass A buckets (over t / dst)
  int KB = (NH + BW - 1) >> BSH;   // pass B buckets (over h / src)
  int B  = (E2 + CHUNK - 1) / CHUNK;

  char* w = (char*)d_ws;
  size_t used = 0;
  auto alloc = [&](size_t bytes) {
    char* p = w + used; used = (used + bytes + 255) & ~(size_t)255; return p;
  };
  __hip_bfloat16* xsA = (__hip_bfloat16*)alloc((size_t)NH * HC * 2);
  __hip_bfloat16* xsB = (__hip_bfloat16*)alloc((size_t)NT * HC * 2);
  float* lsA  = (float*)alloc((size_t)NH * 2 * 4);
  float* ldB  = (float*)alloc((size_t)NH * 2 * 4);
  float* lsB  = (float*)alloc((size_t)NT * 2 * 4);
  float* ldA  = (float*)alloc((size_t)NT * 2 * 4);
  int* histA  = (int*)alloc((size_t)KA * B * 4);
  int* histB  = (int*)alloc((size_t)KB * B * 4);
  int* totals = (int*)alloc((size_t)(KA + KB) * 4);
  int* offA   = (int*)alloc((size_t)(KA + 1) * 4);
  int* offB   = (int*)alloc((size_t)(KB + 1) * 4);
  int* rowT   = (int*)alloc((size_t)(NT + 1) * 4);
  int* rowH   = (int*)alloc((size_t)(NH + 1) * 4);
  unsigned int* partA = (unsigned int*)alloc((size_t)E2 * 4);
  unsigned int* partB = (unsigned int*)alloc((size_t)E2 * 4);
  int* csrT   = (int*)alloc((size_t)E2 * 4);
  int* csrH   = (int*)alloc((size_t)E2 * 4);
  unsigned short* Bt = (unsigned short*)alloc((size_t)80 * DD * 2);

  float* out   = (float*)d_out;              // (h_rep [NH,64], t_rep [NT,64])
  float* out_h = out;
  float* out_t = out + (size_t)NH * HC;

  build_bt<<<80, 128, 0, stream>>>(W_src, W_dst, att_s, att_d, Bt);

  int bH = (NH + 63) / 64, bT = (NT + 63) / 64;
  node_mfma<<<bH + bT, 256, 0, stream>>>(
      h_x, t_x, Bt, xsA, xsB, lsA, ldB, lsB, ldA, NH, NT, bH);

  hist_both<<<B, 256, 0, stream>>>(srcA, dstA, E, NL, histA, histB, KA, KB, B);
  scan_hist<<<(KA + KB + 3) / 4, 256, 0, stream>>>(histA, KA, histB, KB, B, totals);
  scan_totals<<<1, 1024, 0, stream>>>(totals, KA, KB, E2, offA, offB);
  partition_edges<<<dim3(B, 2), 256, 0, stream>>>(
      srcA, dstA, E, NL, histA, offA, histB, offB, partA, partB, KA, KB, B);
  bucket_csr2<<<KA + KB, 256, 0, stream>>>(partA, offA, KA, NT, partB, offB, KB, NH,
                                           E2, csrT, rowT, csrH, rowH);

  // pass A: src=h, dst=t -> t_rep ; pass B: src=t, dst=h -> h_rep
  // 8 dsts per block (4 waves x 2 dsts/wave)
  int gA = (NT + 7) / 8, gB = (NH + 7) / 8;
  csr_message5<<<gA + gB, 256, 0, stream>>>(
      rowT, csrT, lsA, ldA, xsA, out_t, NT,
      rowH, csrH, lsB, ldB, xsB, out_h, NH, bias, gA);
}